// Round 3
// baseline (1066.889 us; speedup 1.0000x reference)
//
#include <hip/hip_runtime.h>
#include <cstdint>

// Problem constants
#define DM   512      // D_MODEL
#define DFF  2048     // D_FF
#define BSZ  4        // batch
#define LSEQ 1024     // sequence length

// ---------- small float4 helpers ----------
__device__ __forceinline__ float4 f4fma(float4 a, float4 b, float4 c) {
    return make_float4(fmaf(a.x, b.x, c.x), fmaf(a.y, b.y, c.y),
                       fmaf(a.z, b.z, c.z), fmaf(a.w, b.w, c.w));
}
__device__ __forceinline__ float4 f4mul(float4 a, float4 b) {
    return make_float4(a.x * b.x, a.y * b.y, a.z * b.z, a.w * b.w);
}

// =====================================================================
// STP scan, lean form. One row per 64-lane wave, 8 f32 state elems/lane.
//
// grid = BSZ * DFF / 4 = 2048 blocks x 256 threads (4 waves, 1 row each).
// Lane owns float4 indices {lane, lane+64} of the 512-float row
// (d = 4*lane+c and 4*(lane+64)+c).
//
// hbuf arrives holding static_h = x@W1^T + b1 (from gemm); the scan
// reads sh[t] (wave-uniform scalar load), computes
//   h_pre = sh + F·x_t ;  F' = R∘F + (G∘x_t)*h_pre
// and overwrites hbuf[t] with h_pre (gelu applied by a later pass).
// No LDS, no barriers, no erff in the loop. State = F,R,G = 24 VGPR;
// target <=64 total for 8 waves/SIMD.
// =====================================================================
__global__ __launch_bounds__(256, 8)
void stp_scan(const float* __restrict__ x,     // (B, L, DM)
              const float* __restrict__ Lam,   // (DFF, DM)
              const float* __restrict__ Gam,   // (DFF, DM)
              float* __restrict__ hbuf)        // (B*L, DFF) in: sh, out: h_pre
{
    const int lane = threadIdx.x & 63;
    const int wid  = __builtin_amdgcn_readfirstlane(threadIdx.x) >> 6;
    const int b    = blockIdx.x >> 9;               // DFF/4 = 512 blocks/batch
    const int f    = ((blockIdx.x & 511) << 2) + wid;

    const float4* __restrict__ x4 =
        reinterpret_cast<const float4*>(x + (size_t)b * LSEQ * DM);
    float* __restrict__ hrow = hbuf + (size_t)b * LSEQ * DFF + f;

    float4 F0 = make_float4(0.f, 0.f, 0.f, 0.f);
    float4 F1 = make_float4(0.f, 0.f, 0.f, 0.f);
    float4 R0, R1, G0, G1;
    {
        const float4* lr = reinterpret_cast<const float4*>(Lam + (size_t)f * DM);
        const float4* gr = reinterpret_cast<const float4*>(Gam + (size_t)f * DM);
        float4 l0 = lr[lane], l1 = lr[lane + 64];
        R0.x = 1.0f / (1.0f + expf(l0.x));   // retention = 1 - sigmoid(Lam)
        R0.y = 1.0f / (1.0f + expf(l0.y));
        R0.z = 1.0f / (1.0f + expf(l0.z));
        R0.w = 1.0f / (1.0f + expf(l0.w));
        R1.x = 1.0f / (1.0f + expf(l1.x));
        R1.y = 1.0f / (1.0f + expf(l1.y));
        R1.z = 1.0f / (1.0f + expf(l1.z));
        R1.w = 1.0f / (1.0f + expf(l1.w));
        G0 = gr[lane];
        G1 = gr[lane + 64];
    }

#define STP_STEP(T, X0, X1)                                               \
    {                                                                     \
        float4 a = f4fma(F0, (X0), make_float4(0.f, 0.f, 0.f, 0.f));      \
        a = f4fma(F1, (X1), a);                                           \
        float p = (a.x + a.y) + (a.z + a.w);                              \
        p += __shfl_xor(p, 1);                                            \
        p += __shfl_xor(p, 2);                                            \
        p += __shfl_xor(p, 4);                                            \
        p += __shfl_xor(p, 8);                                            \
        p += __shfl_xor(p, 16);                                           \
        p += __shfl_xor(p, 32);                                           \
        const float hp = p + hrow[(size_t)(T) * DFF];                     \
        if (lane == 0) hrow[(size_t)(T) * DFF] = hp;                      \
        float4 gx0 = f4mul(G0, (X0));                                     \
        float4 gx1 = f4mul(G1, (X1));                                     \
        float4 rf0 = f4mul(R0, F0);                                       \
        float4 rf1 = f4mul(R1, F1);                                       \
        F0.x = fmaf(gx0.x, hp, rf0.x);                                    \
        F0.y = fmaf(gx0.y, hp, rf0.y);                                    \
        F0.z = fmaf(gx0.z, hp, rf0.z);                                    \
        F0.w = fmaf(gx0.w, hp, rf0.w);                                    \
        F1.x = fmaf(gx1.x, hp, rf1.x);                                    \
        F1.y = fmaf(gx1.y, hp, rf1.y);                                    \
        F1.z = fmaf(gx1.z, hp, rf1.z);                                    \
        F1.w = fmaf(gx1.w, hp, rf1.w);                                    \
    }

    // ping-pong double-step: prefetch x[t+1] while computing step t
    float4 xA0 = x4[lane], xA1 = x4[lane + 64];
    #pragma unroll 1
    for (int t = 0; t < LSEQ; t += 2) {
        float4 xB0 = x4[(t + 1) * 128 + lane];
        float4 xB1 = x4[(t + 1) * 128 + 64 + lane];
        STP_STEP(t, xA0, xA1);
        const int t2 = (t + 2 < LSEQ) ? (t + 2) : (LSEQ - 1);
        xA0 = x4[t2 * 128 + lane];
        xA1 = x4[t2 * 128 + 64 + lane];
        STP_STEP(t + 1, xB0, xB1);
    }
#undef STP_STEP
}

// =====================================================================
// Elementwise exact-gelu pass, in place over hbuf.
// =====================================================================
__global__ __launch_bounds__(256)
void gelu_inplace(float4* __restrict__ p, int n4)
{
    int i = blockIdx.x * blockDim.x + threadIdx.x;
    const int stride = gridDim.x * blockDim.x;
    for (; i < n4; i += stride) {
        float4 v = p[i];
        v.x = 0.5f * v.x * (1.0f + erff(v.x * 0.70710678118654752f));
        v.y = 0.5f * v.y * (1.0f + erff(v.y * 0.70710678118654752f));
        v.z = 0.5f * v.z * (1.0f + erff(v.z * 0.70710678118654752f));
        v.w = 0.5f * v.w * (1.0f + erff(v.w * 0.70710678118654752f));
        p[i] = v;
    }
}

// =====================================================================
// C[M,N] = A[M,K] · B[N,K]^T + bias[N]   (fp32 NT). 64x64 tile, BK=16,
// 256 threads, 4x4 per thread. Used for both static_h and the output.
// =====================================================================
__global__ __launch_bounds__(256)
void gemm_nt_bias(const float* __restrict__ A,
                  const float* __restrict__ Bm,
                  const float* __restrict__ bias,
                  float* __restrict__ C,
                  int M, int N, int K)
{
    __shared__ float As[16][68];
    __shared__ float Bs[16][68];

    const int tid = threadIdx.x;
    const int tx  = tid & 15;
    const int ty  = tid >> 4;
    const int row0 = blockIdx.y * 64;
    const int col0 = blockIdx.x * 64;

    const int lr = tid >> 2;          // 0..63
    const int lk = (tid & 3) << 2;    // 0,4,8,12

    const float* Aptr = A  + (size_t)(row0 + lr) * K + lk;
    const float* Bptr = Bm + (size_t)(col0 + lr) * K + lk;

    float acc[4][4] = {};
    float4 av = *reinterpret_cast<const float4*>(Aptr);
    float4 bv = *reinterpret_cast<const float4*>(Bptr);

    const int NT = K >> 4;
    for (int kt = 0; kt < NT; ++kt) {
        __syncthreads();
        As[lk + 0][lr] = av.x; As[lk + 1][lr] = av.y;
        As[lk + 2][lr] = av.z; As[lk + 3][lr] = av.w;
        Bs[lk + 0][lr] = bv.x; Bs[lk + 1][lr] = bv.y;
        Bs[lk + 2][lr] = bv.z; Bs[lk + 3][lr] = bv.w;
        __syncthreads();

        if (kt + 1 < NT) {
            av = *reinterpret_cast<const float4*>(Aptr + (kt + 1) * 16);
            bv = *reinterpret_cast<const float4*>(Bptr + (kt + 1) * 16);
        }

        #pragma unroll
        for (int k = 0; k < 16; ++k) {
            float4 a = *reinterpret_cast<const float4*>(&As[k][ty * 4]);
            float4 bb = *reinterpret_cast<const float4*>(&Bs[k][tx * 4]);
            acc[0][0] = fmaf(a.x, bb.x, acc[0][0]);
            acc[0][1] = fmaf(a.x, bb.y, acc[0][1]);
            acc[0][2] = fmaf(a.x, bb.z, acc[0][2]);
            acc[0][3] = fmaf(a.x, bb.w, acc[0][3]);
            acc[1][0] = fmaf(a.y, bb.x, acc[1][0]);
            acc[1][1] = fmaf(a.y, bb.y, acc[1][1]);
            acc[1][2] = fmaf(a.y, bb.z, acc[1][2]);
            acc[1][3] = fmaf(a.y, bb.w, acc[1][3]);
            acc[2][0] = fmaf(a.z, bb.x, acc[2][0]);
            acc[2][1] = fmaf(a.z, bb.y, acc[2][1]);
            acc[2][2] = fmaf(a.z, bb.z, acc[2][2]);
            acc[2][3] = fmaf(a.z, bb.w, acc[2][3]);
            acc[3][0] = fmaf(a.w, bb.x, acc[3][0]);
            acc[3][1] = fmaf(a.w, bb.y, acc[3][1]);
            acc[3][2] = fmaf(a.w, bb.z, acc[3][2]);
            acc[3][3] = fmaf(a.w, bb.w, acc[3][3]);
        }
    }

    const float4 bb = *reinterpret_cast<const float4*>(&bias[col0 + tx * 4]);
    #pragma unroll
    for (int i = 0; i < 4; ++i) {
        float4 o;
        o.x = acc[i][0] + bb.x;
        o.y = acc[i][1] + bb.y;
        o.z = acc[i][2] + bb.z;
        o.w = acc[i][3] + bb.w;
        *reinterpret_cast<float4*>(&C[(size_t)(row0 + ty * 4 + i) * N + col0 + tx * 4]) = o;
    }
}

// =====================================================================
extern "C" void kernel_launch(void* const* d_in, const int* in_sizes, int n_in,
                              void* d_out, int out_size, void* d_ws, size_t ws_size,
                              hipStream_t stream)
{
    const float* x   = (const float*)d_in[0];  // (4,1024,512)
    const float* W1  = (const float*)d_in[1];  // (2048,512)
    const float* b1  = (const float*)d_in[2];  // (2048)
    const float* W2  = (const float*)d_in[3];  // (512,2048)
    const float* b2  = (const float*)d_in[4];  // (512)
    const float* Lam = (const float*)d_in[5];  // (2048,512)
    const float* Gam = (const float*)d_in[6];  // (2048,512)
    float* out  = (float*)d_out;               // (4,1024,512)
    float* hbuf = (float*)d_ws;                // (4096, 2048) f32 = 32 MB

    const int M = BSZ * LSEQ;                  // 4096

    // 1) static_h = x @ W1^T + b1  -> hbuf
    gemm_nt_bias<<<dim3(DFF / 64, M / 64), dim3(256), 0, stream>>>(
        x, W1, b1, hbuf, M, DFF, DM);

    // 2) scan: hbuf <- h_pre (in place), 2048 blocks
    stp_scan<<<dim3(BSZ * (DFF / 4)), dim3(256), 0, stream>>>(x, Lam, Gam, hbuf);

    // 3) hbuf <- gelu(hbuf)
    gelu_inplace<<<dim3(2048), dim3(256), 0, stream>>>(
        reinterpret_cast<float4*>(hbuf), M * DFF / 4);

    // 4) out = hbuf @ W2^T + b2
    gemm_nt_bias<<<dim3(DM / 64, M / 64), dim3(256), 0, stream>>>(
        hbuf, W2, b2, out, M, DM, DFF);
}

// Round 4
// 836.361 us; speedup vs baseline: 1.2756x; 1.2756x over previous
//
#include <hip/hip_runtime.h>
#include <cstdint>

// Problem constants
#define DM   512      // D_MODEL
#define DFF  2048     // D_FF
#define BSZ  4        // batch
#define LSEQ 1024     // sequence length

// ---------- small float4 helpers ----------
__device__ __forceinline__ float4 f4fma(float4 a, float4 b, float4 c) {
    return make_float4(fmaf(a.x, b.x, c.x), fmaf(a.y, b.y, c.y),
                       fmaf(a.z, b.z, c.z), fmaf(a.w, b.w, c.w));
}
__device__ __forceinline__ float4 f4mul(float4 a, float4 b) {
    return make_float4(a.x * b.x, a.y * b.y, a.z * b.z, a.w * b.w);
}
__device__ __forceinline__ float4 f4fmas(float4 a, float s, float4 c) {
    return make_float4(fmaf(a.x, s, c.x), fmaf(a.y, s, c.y),
                       fmaf(a.z, s, c.z), fmaf(a.w, s, c.w));
}

// Butterfly sum across each 32-lane half (independent halves).
// xor1/xor2 via DPP quad_perm (VALU only), xor4/8/16 via ds_swizzle
// BitMode (offset = xor_mask<<10 | 0x1F) — 1 DS instr each, no addr calc.
__device__ __forceinline__ float red32(float p) {
    int t;
    t = __builtin_amdgcn_update_dpp(0, __float_as_int(p), 0xB1, 0xF, 0xF, true); // quad_perm [1,0,3,2] = xor 1
    p += __int_as_float(t);
    t = __builtin_amdgcn_update_dpp(0, __float_as_int(p), 0x4E, 0xF, 0xF, true); // quad_perm [2,3,0,1] = xor 2
    p += __int_as_float(t);
    p += __int_as_float(__builtin_amdgcn_ds_swizzle(__float_as_int(p), 0x101F)); // xor 4
    p += __int_as_float(__builtin_amdgcn_ds_swizzle(__float_as_int(p), 0x201F)); // xor 8
    p += __int_as_float(__builtin_amdgcn_ds_swizzle(__float_as_int(p), 0x401F)); // xor 16
    return p;
}

// =====================================================================
// STP scan. 2 rows per 64-lane wave (one per 32-lane half), 16 f32
// state elems per lane (float4 indices j+32k, k=0..3, j = lane&31).
//
// grid = BSZ*DFF/8 = 1024 blocks x 256 threads (4 waves x 2 rows).
// hbuf arrives holding static_h = x@W1^T + b1; the scan reads sh[t]
// (prefetched scalar), computes
//   h_pre = sh + F·x_t ;  F' = R∘F + (G∘x_t)*h_pre
// and overwrites hbuf[t,f] with h_pre (gelu applied by a later pass).
// No LDS tiles, no barriers, no erff in the loop.
// =====================================================================
__global__ __launch_bounds__(256, 4)
void stp_scan(const float* __restrict__ x,     // (B, L, DM)
              const float* __restrict__ Lam,   // (DFF, DM)
              const float* __restrict__ Gam,   // (DFF, DM)
              float* __restrict__ hbuf)        // (B*L, DFF) in: sh, out: h_pre
{
    const int lane = threadIdx.x & 63;
    const int wid  = threadIdx.x >> 6;
    const int j    = lane & 31;          // lane within row-group
    const int h    = lane >> 5;          // which of the wave's 2 rows
    const int b    = blockIdx.x >> 8;    // 256 blocks per batch
    const int f    = ((blockIdx.x & 255) << 3) + (wid << 1) + h;

    const float4* __restrict__ x4 =
        reinterpret_cast<const float4*>(x + (size_t)b * LSEQ * DM);
    float* __restrict__ hrow = hbuf + (size_t)b * LSEQ * DFF + f;

    float4 F0 = make_float4(0.f,0.f,0.f,0.f), F1 = F0, F2 = F0, F3 = F0;
    float4 R0, R1, R2, R3, G0, G1, G2, G3;
    {
        const float4* lr = reinterpret_cast<const float4*>(Lam + (size_t)f * DM);
        const float4* gr = reinterpret_cast<const float4*>(Gam + (size_t)f * DM);
        float4 l0 = lr[j], l1 = lr[j + 32], l2 = lr[j + 64], l3 = lr[j + 96];
        #define SIGM(dst, src)                                   \
            dst.x = 1.0f / (1.0f + expf(src.x));                 \
            dst.y = 1.0f / (1.0f + expf(src.y));                 \
            dst.z = 1.0f / (1.0f + expf(src.z));                 \
            dst.w = 1.0f / (1.0f + expf(src.w));
        SIGM(R0, l0) SIGM(R1, l1) SIGM(R2, l2) SIGM(R3, l3)
        #undef SIGM
        G0 = gr[j]; G1 = gr[j + 32]; G2 = gr[j + 64]; G3 = gr[j + 96];
    }

#define STP_STEP(T, Xa, Xb, Xc, Xd, SH)                                   \
    {                                                                     \
        float4 a = f4fma(F1, (Xb), f4mul(F0, (Xa)));                      \
        float4 c = f4fma(F3, (Xd), f4mul(F2, (Xc)));                      \
        a.x += c.x; a.y += c.y; a.z += c.z; a.w += c.w;                   \
        float p = (a.x + a.y) + (a.z + a.w);                              \
        p = red32(p);                                                     \
        const float hp = p + (SH);                                        \
        if (j == 0) hrow[(size_t)(T) * DFF] = hp;                         \
        float4 t0 = f4mul(R0, F0), g0 = f4mul(G0, (Xa));                  \
        float4 t1 = f4mul(R1, F1), g1 = f4mul(G1, (Xb));                  \
        float4 t2 = f4mul(R2, F2), g2 = f4mul(G2, (Xc));                  \
        float4 t3 = f4mul(R3, F3), g3 = f4mul(G3, (Xd));                  \
        F0 = f4fmas(g0, hp, t0);                                          \
        F1 = f4fmas(g1, hp, t1);                                          \
        F2 = f4fmas(g2, hp, t2);                                          \
        F3 = f4fmas(g3, hp, t3);                                          \
    }

    // prime step 0
    float4 xA0 = x4[j], xA1 = x4[j + 32], xA2 = x4[j + 64], xA3 = x4[j + 96];
    float  shA = hrow[0];

    #pragma unroll 1
    for (int t = 0; t < LSEQ; t += 2) {
        // prefetch step t+1 (x and sh) before computing step t
        const int o1 = (t + 1) * 128;
        float4 xB0 = x4[o1 + j],      xB1 = x4[o1 + 32 + j];
        float4 xB2 = x4[o1 + 64 + j], xB3 = x4[o1 + 96 + j];
        float  shB = hrow[(size_t)(t + 1) * DFF];

        STP_STEP(t, xA0, xA1, xA2, xA3, shA)

        const int t2 = (t + 2 < LSEQ) ? (t + 2) : (LSEQ - 1);
        const int o2 = t2 * 128;
        xA0 = x4[o2 + j];      xA1 = x4[o2 + 32 + j];
        xA2 = x4[o2 + 64 + j]; xA3 = x4[o2 + 96 + j];
        shA = hrow[(size_t)t2 * DFF];

        STP_STEP(t + 1, xB0, xB1, xB2, xB3, shB)
    }
#undef STP_STEP
}

// =====================================================================
// Elementwise exact-gelu pass, in place over hbuf.
// =====================================================================
__global__ __launch_bounds__(256)
void gelu_inplace(float4* __restrict__ p, int n4)
{
    int i = blockIdx.x * blockDim.x + threadIdx.x;
    const int stride = gridDim.x * blockDim.x;
    for (; i < n4; i += stride) {
        float4 v = p[i];
        v.x = 0.5f * v.x * (1.0f + erff(v.x * 0.70710678118654752f));
        v.y = 0.5f * v.y * (1.0f + erff(v.y * 0.70710678118654752f));
        v.z = 0.5f * v.z * (1.0f + erff(v.z * 0.70710678118654752f));
        v.w = 0.5f * v.w * (1.0f + erff(v.w * 0.70710678118654752f));
        p[i] = v;
    }
}

// =====================================================================
// C[M,N] = A[M,K] · B[N,K]^T + bias[N]   (fp32 NT). 64x64 tile, BK=16,
// 256 threads, 4x4 per thread. Used for both static_h and the output.
// =====================================================================
__global__ __launch_bounds__(256)
void gemm_nt_bias(const float* __restrict__ A,
                  const float* __restrict__ Bm,
                  const float* __restrict__ bias,
                  float* __restrict__ C,
                  int M, int N, int K)
{
    __shared__ float As[16][68];
    __shared__ float Bs[16][68];

    const int tid = threadIdx.x;
    const int tx  = tid & 15;
    const int ty  = tid >> 4;
    const int row0 = blockIdx.y * 64;
    const int col0 = blockIdx.x * 64;

    const int lr = tid >> 2;          // 0..63
    const int lk = (tid & 3) << 2;    // 0,4,8,12

    const float* Aptr = A  + (size_t)(row0 + lr) * K + lk;
    const float* Bptr = Bm + (size_t)(col0 + lr) * K + lk;

    float acc[4][4] = {};
    float4 av = *reinterpret_cast<const float4*>(Aptr);
    float4 bv = *reinterpret_cast<const float4*>(Bptr);

    const int NT = K >> 4;
    for (int kt = 0; kt < NT; ++kt) {
        __syncthreads();
        As[lk + 0][lr] = av.x; As[lk + 1][lr] = av.y;
        As[lk + 2][lr] = av.z; As[lk + 3][lr] = av.w;
        Bs[lk + 0][lr] = bv.x; Bs[lk + 1][lr] = bv.y;
        Bs[lk + 2][lr] = bv.z; Bs[lk + 3][lr] = bv.w;
        __syncthreads();

        if (kt + 1 < NT) {
            av = *reinterpret_cast<const float4*>(Aptr + (kt + 1) * 16);
            bv = *reinterpret_cast<const float4*>(Bptr + (kt + 1) * 16);
        }

        #pragma unroll
        for (int k = 0; k < 16; ++k) {
            float4 a = *reinterpret_cast<const float4*>(&As[k][ty * 4]);
            float4 bb = *reinterpret_cast<const float4*>(&Bs[k][tx * 4]);
            acc[0][0] = fmaf(a.x, bb.x, acc[0][0]);
            acc[0][1] = fmaf(a.x, bb.y, acc[0][1]);
            acc[0][2] = fmaf(a.x, bb.z, acc[0][2]);
            acc[0][3] = fmaf(a.x, bb.w, acc[0][3]);
            acc[1][0] = fmaf(a.y, bb.x, acc[1][0]);
            acc[1][1] = fmaf(a.y, bb.y, acc[1][1]);
            acc[1][2] = fmaf(a.y, bb.z, acc[1][2]);
            acc[1][3] = fmaf(a.y, bb.w, acc[1][3]);
            acc[2][0] = fmaf(a.z, bb.x, acc[2][0]);
            acc[2][1] = fmaf(a.z, bb.y, acc[2][1]);
            acc[2][2] = fmaf(a.z, bb.z, acc[2][2]);
            acc[2][3] = fmaf(a.z, bb.w, acc[2][3]);
            acc[3][0] = fmaf(a.w, bb.x, acc[3][0]);
            acc[3][1] = fmaf(a.w, bb.y, acc[3][1]);
            acc[3][2] = fmaf(a.w, bb.z, acc[3][2]);
            acc[3][3] = fmaf(a.w, bb.w, acc[3][3]);
        }
    }

    const float4 bb = *reinterpret_cast<const float4*>(&bias[col0 + tx * 4]);
    #pragma unroll
    for (int i = 0; i < 4; ++i) {
        float4 o;
        o.x = acc[i][0] + bb.x;
        o.y = acc[i][1] + bb.y;
        o.z = acc[i][2] + bb.z;
        o.w = acc[i][3] + bb.w;
        *reinterpret_cast<float4*>(&C[(size_t)(row0 + ty * 4 + i) * N + col0 + tx * 4]) = o;
    }
}

// =====================================================================
extern "C" void kernel_launch(void* const* d_in, const int* in_sizes, int n_in,
                              void* d_out, int out_size, void* d_ws, size_t ws_size,
                              hipStream_t stream)
{
    const float* x   = (const float*)d_in[0];  // (4,1024,512)
    const float* W1  = (const float*)d_in[1];  // (2048,512)
    const float* b1  = (const float*)d_in[2];  // (2048)
    const float* W2  = (const float*)d_in[3];  // (512,2048)
    const float* b2  = (const float*)d_in[4];  // (512)
    const float* Lam = (const float*)d_in[5];  // (2048,512)
    const float* Gam = (const float*)d_in[6];  // (2048,512)
    float* out  = (float*)d_out;               // (4,1024,512)
    float* hbuf = (float*)d_ws;                // (4096, 2048) f32 = 32 MB

    const int M = BSZ * LSEQ;                  // 4096

    // 1) static_h = x @ W1^T + b1  -> hbuf
    gemm_nt_bias<<<dim3(DFF / 64, M / 64), dim3(256), 0, stream>>>(
        x, W1, b1, hbuf, M, DFF, DM);

    // 2) scan: hbuf <- h_pre (in place), 1024 blocks x 4 waves x 2 rows
    stp_scan<<<dim3(BSZ * (DFF / 8)), dim3(256), 0, stream>>>(x, Lam, Gam, hbuf);

    // 3) hbuf <- gelu(hbuf)
    gelu_inplace<<<dim3(2048), dim3(256), 0, stream>>>(
        reinterpret_cast<float4*>(hbuf), M * DFF / 4);

    // 4) out = hbuf @ W2^T + b2
    gemm_nt_bias<<<dim3(DM / 64, M / 64), dim3(256), 0, stream>>>(
        hbuf, W2, b2, out, M, DM, DFF);
}

// Round 5
// 777.889 us; speedup vs baseline: 1.3715x; 1.0752x over previous
//
#include <hip/hip_runtime.h>
#include <cstdint>

// Problem constants
#define DM   512      // D_MODEL
#define DFF  2048     // D_FF
#define BSZ  4        // batch
#define LSEQ 1024     // sequence length

typedef __attribute__((ext_vector_type(2))) float f32x2;

// ---------- packed fp32 (VOP3P, full-rate on CDNA) ----------
__device__ __forceinline__ f32x2 pk_mul(f32x2 a, f32x2 b) {
    f32x2 d;
    asm("v_pk_mul_f32 %0, %1, %2" : "=v"(d) : "v"(a), "v"(b));
    return d;
}
__device__ __forceinline__ f32x2 pk_fma(f32x2 a, f32x2 b, f32x2 c) {
    f32x2 d;
    asm("v_pk_fma_f32 %0, %1, %2, %3" : "=v"(d) : "v"(a), "v"(b), "v"(c));
    return d;
}
__device__ __forceinline__ f32x2 pk_add(f32x2 a, f32x2 b) {
    f32x2 d;
    asm("v_pk_add_f32 %0, %1, %2" : "=v"(d) : "v"(a), "v"(b));
    return d;
}

// p += dpp-shifted p (bound_ctrl=0 -> OOB lanes contribute 0)
#define DPP_ADD(p, ctrl)                                                     \
    p += __int_as_float(__builtin_amdgcn_update_dpp(                         \
        0, __float_as_int(p), (ctrl), 0xF, 0xF, true))

// =====================================================================
// STP scan. 2 rows per 64-lane wave (one per 32-lane half), 16 f32
// state elems per lane: row f's float4 indices {j, j+32, j+64, j+96},
// j = lane&31. grid = BSZ*DFF/8 = 1024 blocks x 256 thr (4 waves).
//
// hbuf arrives holding static_h = x@W1^T + b1; per step:
//   h_pre = sh_t + F·x_t ;  F' = R∘F + (G∘x_t)*h_pre
// hbuf[t,f] is overwritten with h_pre (gelu applied by a later pass).
//
// x_t staged in double-buffered LDS (2KB), one barrier/step; loads
// prefetched 2 steps ahead. Reduction: DPP row_shr scan (+bcast15)
// -> half-sums in lanes 31/63 -> ds_swizzle(0x3E0) broadcast.
// Dot + update in v_pk_*_f32 packed math.
// =====================================================================
__global__ __launch_bounds__(256, 4)
void stp_scan(const float* __restrict__ x,     // (B, L, DM)
              const float* __restrict__ Lam,   // (DFF, DM)
              const float* __restrict__ Gam,   // (DFF, DM)
              float* __restrict__ hbuf)        // (B*L, DFF) in: sh, out: h_pre
{
    const int tid  = threadIdx.x;
    const int lane = tid & 63;
    const int wid  = tid >> 6;
    const int j    = lane & 31;          // lane within row
    const int h    = lane >> 5;          // which of the wave's 2 rows
    const int b    = blockIdx.x >> 8;    // 256 blocks per batch
    const int f    = ((blockIdx.x & 255) << 3) + (wid << 1) + h;

    __shared__ float4 xs[2][128];        // 2 x 2KB x_t buffers

    const float4* __restrict__ x4g =
        reinterpret_cast<const float4*>(x + (size_t)b * LSEQ * DM);
    float* __restrict__ hbase = hbuf + (size_t)b * LSEQ * DFF;

    // ---- state: F, R, G as 8 f32x2 each (16 elems/lane) ----
    f32x2 F[8], R[8], G[8];
    {
        const float4* lr = reinterpret_cast<const float4*>(Lam + (size_t)f * DM);
        const float4* gr = reinterpret_cast<const float4*>(Gam + (size_t)f * DM);
        #pragma unroll
        for (int k = 0; k < 4; ++k) {
            float4 lv = lr[j + 32 * k];
            float4 gv = gr[j + 32 * k];
            f32x2 r0, r1;
            r0.x = 1.0f / (1.0f + expf(lv.x));   // retention = 1 - sigmoid(Lam)
            r0.y = 1.0f / (1.0f + expf(lv.y));
            r1.x = 1.0f / (1.0f + expf(lv.z));
            r1.y = 1.0f / (1.0f + expf(lv.w));
            R[2 * k] = r0;   R[2 * k + 1] = r1;
            f32x2 g0; g0.x = gv.x; g0.y = gv.y;
            f32x2 g1; g1.x = gv.z; g1.y = gv.w;
            G[2 * k] = g0;   G[2 * k + 1] = g1;
            f32x2 z; z.x = 0.f; z.y = 0.f;
            F[2 * k] = z;    F[2 * k + 1] = z;
        }
    }

// one scan step reading xs[CUR] with static_h value SHV
#define STP_STEP(T, CUR, SHV)                                                 \
    {                                                                         \
        float4 q0 = xs[CUR][j];                                               \
        float4 q1 = xs[CUR][j + 32];                                          \
        float4 q2 = xs[CUR][j + 64];                                          \
        float4 q3 = xs[CUR][j + 96];                                          \
        f32x2 x0 = *(f32x2*)&q0.x, x1 = *(f32x2*)&q0.z;                       \
        f32x2 x2 = *(f32x2*)&q1.x, x3 = *(f32x2*)&q1.z;                       \
        f32x2 x4_ = *(f32x2*)&q2.x, x5 = *(f32x2*)&q2.z;                      \
        f32x2 x6 = *(f32x2*)&q3.x, x7 = *(f32x2*)&q3.z;                       \
        f32x2 a0 = pk_mul(F[0], x0); f32x2 a1 = pk_mul(F[2], x2);             \
        a0 = pk_fma(F[1], x1, a0);   a1 = pk_fma(F[3], x3, a1);               \
        a0 = pk_fma(F[4], x4_, a0);  a1 = pk_fma(F[5], x5, a1);               \
        a0 = pk_fma(F[6], x6, a0);   a1 = pk_fma(F[7], x7, a1);               \
        f32x2 asum = pk_add(a0, a1);                                          \
        float p = asum.x + asum.y;                                            \
        DPP_ADD(p, 0x111);  /* row_shr:1  */                                  \
        DPP_ADD(p, 0x112);  /* row_shr:2  */                                  \
        DPP_ADD(p, 0x114);  /* row_shr:4  */                                  \
        DPP_ADD(p, 0x118);  /* row_shr:8  */                                  \
        DPP_ADD(p, 0x142);  /* row_bcast15: lane31|63 = half sums */          \
        float hpv = __int_as_float(                                           \
            __builtin_amdgcn_ds_swizzle(__float_as_int(p), 0x3E0)) + (SHV);   \
        if (j == 0) hbase[(size_t)(T) * DFF + f] = hpv;                       \
        f32x2 hp2; hp2.x = hpv; hp2.y = hpv;                                  \
        F[0] = pk_fma(pk_mul(G[0], x0), hp2, pk_mul(R[0], F[0]));             \
        F[1] = pk_fma(pk_mul(G[1], x1), hp2, pk_mul(R[1], F[1]));             \
        F[2] = pk_fma(pk_mul(G[2], x2), hp2, pk_mul(R[2], F[2]));             \
        F[3] = pk_fma(pk_mul(G[3], x3), hp2, pk_mul(R[3], F[3]));             \
        F[4] = pk_fma(pk_mul(G[4], x4_), hp2, pk_mul(R[4], F[4]));            \
        F[5] = pk_fma(pk_mul(G[5], x5), hp2, pk_mul(R[5], F[5]));             \
        F[6] = pk_fma(pk_mul(G[6], x6), hp2, pk_mul(R[6], F[6]));             \
        F[7] = pk_fma(pk_mul(G[7], x7), hp2, pk_mul(R[7], F[7]));             \
    }

    // ---- prologue: xs[0] <- x_0; stgA <- x_1; shA/shB <- sh_0/sh_1 ----
    float4 stgA, stgB;
    if (tid < 128) {
        xs[0][tid] = x4g[tid];
        stgA = x4g[128 + tid];
    }
    float shA = hbase[f];
    float shB = hbase[(size_t)DFF + f];
    __syncthreads();

    #pragma unroll 1
    for (int t = 0; t < LSEQ; t += 2) {
        // even step t: read xs[0], consume shA, publish x_{t+1} (stgA)
        STP_STEP(t, 0, shA)
        if (tid < 128) xs[1][tid] = stgA;
        __syncthreads();
        {   // prefetch x_{t+2} (to stgB) and sh_{t+2} (to shA)
            const int tl = (t + 2 < LSEQ) ? t + 2 : LSEQ - 1;
            if (tid < 128) stgB = x4g[tl * 128 + tid];
            shA = hbase[(size_t)tl * DFF + f];
        }
        // odd step t+1: read xs[1], consume shB, publish x_{t+2} (stgB)
        STP_STEP(t + 1, 1, shB)
        if (tid < 128) xs[0][tid] = stgB;
        __syncthreads();
        {   // prefetch x_{t+3} (to stgA) and sh_{t+3} (to shB)
            const int tl = (t + 3 < LSEQ) ? t + 3 : LSEQ - 1;
            if (tid < 128) stgA = x4g[tl * 128 + tid];
            shB = hbase[(size_t)tl * DFF + f];
        }
    }
#undef STP_STEP
}

// =====================================================================
// Elementwise exact-gelu pass, in place over hbuf.
// =====================================================================
__global__ __launch_bounds__(256)
void gelu_inplace(float4* __restrict__ p, int n4)
{
    int i = blockIdx.x * blockDim.x + threadIdx.x;
    const int stride = gridDim.x * blockDim.x;
    for (; i < n4; i += stride) {
        float4 v = p[i];
        v.x = 0.5f * v.x * (1.0f + erff(v.x * 0.70710678118654752f));
        v.y = 0.5f * v.y * (1.0f + erff(v.y * 0.70710678118654752f));
        v.z = 0.5f * v.z * (1.0f + erff(v.z * 0.70710678118654752f));
        v.w = 0.5f * v.w * (1.0f + erff(v.w * 0.70710678118654752f));
        p[i] = v;
    }
}

// =====================================================================
// C[M,N] = A[M,K] · B[N,K]^T + bias[N]   (fp32 NT). 64x64 tile, BK=16,
// 256 threads, 4x4 per thread. Used for both static_h and the output.
// =====================================================================
__global__ __launch_bounds__(256)
void gemm_nt_bias(const float* __restrict__ A,
                  const float* __restrict__ Bm,
                  const float* __restrict__ bias,
                  float* __restrict__ C,
                  int M, int N, int K)
{
    __shared__ float As[16][68];
    __shared__ float Bs[16][68];

    const int tid = threadIdx.x;
    const int tx  = tid & 15;
    const int ty  = tid >> 4;
    const int row0 = blockIdx.y * 64;
    const int col0 = blockIdx.x * 64;

    const int lr = tid >> 2;          // 0..63
    const int lk = (tid & 3) << 2;    // 0,4,8,12

    const float* Aptr = A  + (size_t)(row0 + lr) * K + lk;
    const float* Bptr = Bm + (size_t)(col0 + lr) * K + lk;

    float acc[4][4] = {};
    float4 av = *reinterpret_cast<const float4*>(Aptr);
    float4 bv = *reinterpret_cast<const float4*>(Bptr);

    const int NT = K >> 4;
    for (int kt = 0; kt < NT; ++kt) {
        __syncthreads();
        As[lk + 0][lr] = av.x; As[lk + 1][lr] = av.y;
        As[lk + 2][lr] = av.z; As[lk + 3][lr] = av.w;
        Bs[lk + 0][lr] = bv.x; Bs[lk + 1][lr] = bv.y;
        Bs[lk + 2][lr] = bv.z; Bs[lk + 3][lr] = bv.w;
        __syncthreads();

        if (kt + 1 < NT) {
            av = *reinterpret_cast<const float4*>(Aptr + (kt + 1) * 16);
            bv = *reinterpret_cast<const float4*>(Bptr + (kt + 1) * 16);
        }

        #pragma unroll
        for (int k = 0; k < 16; ++k) {
            float4 a = *reinterpret_cast<const float4*>(&As[k][ty * 4]);
            float4 bb = *reinterpret_cast<const float4*>(&Bs[k][tx * 4]);
            acc[0][0] = fmaf(a.x, bb.x, acc[0][0]);
            acc[0][1] = fmaf(a.x, bb.y, acc[0][1]);
            acc[0][2] = fmaf(a.x, bb.z, acc[0][2]);
            acc[0][3] = fmaf(a.x, bb.w, acc[0][3]);
            acc[1][0] = fmaf(a.y, bb.x, acc[1][0]);
            acc[1][1] = fmaf(a.y, bb.y, acc[1][1]);
            acc[1][2] = fmaf(a.y, bb.z, acc[1][2]);
            acc[1][3] = fmaf(a.y, bb.w, acc[1][3]);
            acc[2][0] = fmaf(a.z, bb.x, acc[2][0]);
            acc[2][1] = fmaf(a.z, bb.y, acc[2][1]);
            acc[2][2] = fmaf(a.z, bb.z, acc[2][2]);
            acc[2][3] = fmaf(a.z, bb.w, acc[2][3]);
            acc[3][0] = fmaf(a.w, bb.x, acc[3][0]);
            acc[3][1] = fmaf(a.w, bb.y, acc[3][1]);
            acc[3][2] = fmaf(a.w, bb.z, acc[3][2]);
            acc[3][3] = fmaf(a.w, bb.w, acc[3][3]);
        }
    }

    const float4 bb = *reinterpret_cast<const float4*>(&bias[col0 + tx * 4]);
    #pragma unroll
    for (int i = 0; i < 4; ++i) {
        float4 o;
        o.x = acc[i][0] + bb.x;
        o.y = acc[i][1] + bb.y;
        o.z = acc[i][2] + bb.z;
        o.w = acc[i][3] + bb.w;
        *reinterpret_cast<float4*>(&C[(size_t)(row0 + ty * 4 + i) * N + col0 + tx * 4]) = o;
    }
}

// =====================================================================
extern "C" void kernel_launch(void* const* d_in, const int* in_sizes, int n_in,
                              void* d_out, int out_size, void* d_ws, size_t ws_size,
                              hipStream_t stream)
{
    const float* x   = (const float*)d_in[0];  // (4,1024,512)
    const float* W1  = (const float*)d_in[1];  // (2048,512)
    const float* b1  = (const float*)d_in[2];  // (2048)
    const float* W2  = (const float*)d_in[3];  // (512,2048)
    const float* b2  = (const float*)d_in[4];  // (512)
    const float* Lam = (const float*)d_in[5];  // (2048,512)
    const float* Gam = (const float*)d_in[6];  // (2048,512)
    float* out  = (float*)d_out;               // (4,1024,512)
    float* hbuf = (float*)d_ws;                // (4096, 2048) f32 = 32 MB

    const int M = BSZ * LSEQ;                  // 4096

    // 1) static_h = x @ W1^T + b1  -> hbuf
    gemm_nt_bias<<<dim3(DFF / 64, M / 64), dim3(256), 0, stream>>>(
        x, W1, b1, hbuf, M, DFF, DM);

    // 2) scan: hbuf <- h_pre (in place)
    stp_scan<<<dim3(BSZ * (DFF / 8)), dim3(256), 0, stream>>>(x, Lam, Gam, hbuf);

    // 3) hbuf <- gelu(hbuf)
    gelu_inplace<<<dim3(2048), dim3(256), 0, stream>>>(
        reinterpret_cast<float4*>(hbuf), M * DFF / 4);

    // 4) out = hbuf @ W2^T + b2
    gemm_nt_bias<<<dim3(DM / 64, M / 64), dim3(256), 0, stream>>>(
        hbuf, W2, b2, out, M, DM, DFF);
}

// Round 6
// 768.182 us; speedup vs baseline: 1.3888x; 1.0126x over previous
//
#include <hip/hip_runtime.h>
#include <cstdint>

// Problem constants
#define DM   512      // D_MODEL
#define DFF  2048     // D_FF
#define BSZ  4        // batch
#define LSEQ 1024     // sequence length
#define CHUNK 8       // timesteps staged per LDS buffer
#define NCHUNK (LSEQ / CHUNK)

typedef __attribute__((ext_vector_type(2))) float f32x2;

// ---------- packed fp32 (VOP3P; same elem-rate as scalar, half the instrs) ----
__device__ __forceinline__ f32x2 pk_mul(f32x2 a, f32x2 b) {
    f32x2 d;
    asm("v_pk_mul_f32 %0, %1, %2" : "=v"(d) : "v"(a), "v"(b));
    return d;
}
__device__ __forceinline__ f32x2 pk_fma(f32x2 a, f32x2 b, f32x2 c) {
    f32x2 d;
    asm("v_pk_fma_f32 %0, %1, %2, %3" : "=v"(d) : "v"(a), "v"(b), "v"(c));
    return d;
}
__device__ __forceinline__ f32x2 pk_add(f32x2 a, f32x2 b) {
    f32x2 d;
    asm("v_pk_add_f32 %0, %1, %2" : "=v"(d) : "v"(a), "v"(b));
    return d;
}

// p += dpp-shifted p (bound_ctrl=true -> OOB lanes contribute 0)
#define DPP_ADD(p, ctrl)                                                     \
    p += __int_as_float(__builtin_amdgcn_update_dpp(                         \
        0, __float_as_int(p), (ctrl), 0xF, 0xF, true))

// =====================================================================
// STP scan. 2 rows per 64-lane wave (one per 32-lane half), 16 f32
// state elems/lane (row f's float4 indices {j, j+32, j+64, j+96},
// j = lane&31). grid = BSZ*DFF/8 = 1024 blocks x 256 thr (4 waves).
//
// hbuf arrives holding static_h = x@W1^T + b1; per step:
//   h_pre = sh_t + F.x_t ;  F' = R o F + (G o x_t)*h_pre
// hbuf[t,f] is overwritten with h_pre (gelu applied by a later pass).
//
// x staged in CHUNK-step double-buffered LDS (2x16KB): ONE barrier per
// 8 steps. sh values prefetched one chunk ahead via pointer-bump;
// h_pre stored via a second bumped pointer. LDS reads use immediate
// offsets (unrolled inner loop). Reduction: DPP row_shr scan + bcast15
// -> 32-lane sums in lanes 31/63 -> ds_swizzle(0x3E0) broadcast.
// =====================================================================
__global__ __launch_bounds__(256, 4)
void stp_scan(const float* __restrict__ x,     // (B, L, DM)
              const float* __restrict__ Lam,   // (DFF, DM)
              const float* __restrict__ Gam,   // (DFF, DM)
              float* __restrict__ hbuf)        // (B*L, DFF) in: sh, out: h_pre
{
    const int tid  = threadIdx.x;
    const int lane = tid & 63;
    const int wid  = tid >> 6;
    const int j    = lane & 31;          // lane within row
    const int h    = lane >> 5;          // which of the wave's 2 rows
    const int b    = blockIdx.x >> 8;    // 256 blocks per batch
    const int f    = ((blockIdx.x & 255) << 3) + (wid << 1) + h;

    __shared__ float4 xs[2][CHUNK * 128];   // 2 x 16KB

    const float4* __restrict__ x4g =
        reinterpret_cast<const float4*>(x + (size_t)b * LSEQ * DM);
    float* __restrict__ hbase = hbuf + (size_t)b * LSEQ * DFF;

    // ---- state: F, R, G as 8 f32x2 each (16 elems/lane) ----
    f32x2 F[8], R[8], G[8];
    {
        const float4* lr = reinterpret_cast<const float4*>(Lam + (size_t)f * DM);
        const float4* gr = reinterpret_cast<const float4*>(Gam + (size_t)f * DM);
        #pragma unroll
        for (int k = 0; k < 4; ++k) {
            float4 lv = lr[j + 32 * k];
            float4 gv = gr[j + 32 * k];
            f32x2 r0, r1;
            r0.x = 1.0f / (1.0f + expf(lv.x));   // retention = 1 - sigmoid(Lam)
            r0.y = 1.0f / (1.0f + expf(lv.y));
            r1.x = 1.0f / (1.0f + expf(lv.z));
            r1.y = 1.0f / (1.0f + expf(lv.w));
            R[2 * k] = r0;   R[2 * k + 1] = r1;
            f32x2 g0; g0.x = gv.x; g0.y = gv.y;
            f32x2 g1; g1.x = gv.z; g1.y = gv.w;
            G[2 * k] = g0;   G[2 * k + 1] = g1;
            f32x2 z; z.x = 0.f; z.y = 0.f;
            F[2 * k] = z;    F[2 * k + 1] = z;
        }
    }

    // ---- prologue: xs[0] <- chunk 0; s-regs <- chunk 1; shc <- sh[0..7] ----
    float4 s0, s1, s2, s3;
    {
        const float4* xsp = x4g + tid;
        float4 t0 = xsp[0], t1 = xsp[256], t2 = xsp[512], t3 = xsp[768];
        float4* xw = &xs[0][0];
        xw[tid] = t0; xw[tid + 256] = t1; xw[tid + 512] = t2; xw[tid + 768] = t3;
        s0 = xsp[1024]; s1 = xsp[1280]; s2 = xsp[1536]; s3 = xsp[1792];
    }
    float shc[CHUNK], shn[CHUNK];
    #pragma unroll
    for (int k = 0; k < CHUNK; ++k) shc[k] = hbase[(size_t)k * DFF + f];
    __syncthreads();

    float* pst = hbase + f;                 // h_pre store pointer (bumped)

    #pragma unroll 1
    for (int c = 0; c < NCHUNK; ++c) {
        const float4* __restrict__ xb = &xs[c & 1][0];
        // sh prefetch pointer for chunk c+1 (clamped re-read of t=0 on last)
        const int cn = (c + 1 < NCHUNK) ? (c + 1) : 0;
        const float* pp = hbase + f + (size_t)cn * (CHUNK * DFF);

        #pragma unroll
        for (int s = 0; s < CHUNK; ++s) {
            float4 q0 = xb[s * 128 + j];
            float4 q1 = xb[s * 128 + j + 32];
            float4 q2 = xb[s * 128 + j + 64];
            float4 q3 = xb[s * 128 + j + 96];
            shn[s] = *pp; pp += DFF;         // prefetch next chunk's sh

            f32x2 x0 = *(f32x2*)&q0.x, x1 = *(f32x2*)&q0.z;
            f32x2 x2 = *(f32x2*)&q1.x, x3 = *(f32x2*)&q1.z;
            f32x2 x4_ = *(f32x2*)&q2.x, x5 = *(f32x2*)&q2.z;
            f32x2 x6 = *(f32x2*)&q3.x, x7 = *(f32x2*)&q3.z;

            // dot(F, x): 2 chains
            f32x2 a0 = pk_mul(F[0], x0); f32x2 a1 = pk_mul(F[2], x2);
            a0 = pk_fma(F[1], x1, a0);   a1 = pk_fma(F[3], x3, a1);
            a0 = pk_fma(F[4], x4_, a0);  a1 = pk_fma(F[5], x5, a1);
            a0 = pk_fma(F[6], x6, a0);   a1 = pk_fma(F[7], x7, a1);
            f32x2 asum = pk_add(a0, a1);
            float p = asum.x + asum.y;

            DPP_ADD(p, 0x111);  // row_shr:1
            DPP_ADD(p, 0x112);  // row_shr:2
            DPP_ADD(p, 0x114);  // row_shr:4
            DPP_ADD(p, 0x118);  // row_shr:8
            DPP_ADD(p, 0x142);  // row_bcast15 -> lanes 31/63 hold half-sums
            const float hpv = __int_as_float(
                __builtin_amdgcn_ds_swizzle(__float_as_int(p), 0x3E0)) + shc[s];

            if (j == 0) *pst = hpv;
            pst += DFF;

            f32x2 hp2; hp2.x = hpv; hp2.y = hpv;
            F[0] = pk_fma(pk_mul(G[0], x0), hp2, pk_mul(R[0], F[0]));
            F[1] = pk_fma(pk_mul(G[1], x1), hp2, pk_mul(R[1], F[1]));
            F[2] = pk_fma(pk_mul(G[2], x2), hp2, pk_mul(R[2], F[2]));
            F[3] = pk_fma(pk_mul(G[3], x3), hp2, pk_mul(R[3], F[3]));
            F[4] = pk_fma(pk_mul(G[4], x4_), hp2, pk_mul(R[4], F[4]));
            F[5] = pk_fma(pk_mul(G[5], x5), hp2, pk_mul(R[5], F[5]));
            F[6] = pk_fma(pk_mul(G[6], x6), hp2, pk_mul(R[6], F[6]));
            F[7] = pk_fma(pk_mul(G[7], x7), hp2, pk_mul(R[7], F[7]));
        }

        // stage chunk c+1 (held in s-regs) into the other buffer, 1 barrier
        {
            float4* xw = &xs[(c + 1) & 1][0];
            xw[tid] = s0; xw[tid + 256] = s1;
            xw[tid + 512] = s2; xw[tid + 768] = s3;
        }
        __syncthreads();

        // prefetch chunk c+2 into s-regs (clamped; consumed next chunk end)
        {
            const int cp = (c + 2 < NCHUNK) ? (c + 2) : (NCHUNK - 1);
            const float4* xsp = x4g + (size_t)cp * (CHUNK * 128) + tid;
            s0 = xsp[0]; s1 = xsp[256]; s2 = xsp[512]; s3 = xsp[768];
        }
        #pragma unroll
        for (int k = 0; k < CHUNK; ++k) shc[k] = shn[k];
    }
}

// =====================================================================
// Elementwise exact-gelu pass, in place over hbuf.
// =====================================================================
__global__ __launch_bounds__(256)
void gelu_inplace(float4* __restrict__ p, int n4)
{
    int i = blockIdx.x * blockDim.x + threadIdx.x;
    const int stride = gridDim.x * blockDim.x;
    for (; i < n4; i += stride) {
        float4 v = p[i];
        v.x = 0.5f * v.x * (1.0f + erff(v.x * 0.70710678118654752f));
        v.y = 0.5f * v.y * (1.0f + erff(v.y * 0.70710678118654752f));
        v.z = 0.5f * v.z * (1.0f + erff(v.z * 0.70710678118654752f));
        v.w = 0.5f * v.w * (1.0f + erff(v.w * 0.70710678118654752f));
        p[i] = v;
    }
}

// =====================================================================
// C[M,N] = A[M,K] . B[N,K]^T + bias[N]   (fp32 NT). 64x64 tile, BK=16,
// 256 threads, 4x4 per thread. Used for both static_h and the output.
// =====================================================================
__global__ __launch_bounds__(256)
void gemm_nt_bias(const float* __restrict__ A,
                  const float* __restrict__ Bm,
                  const float* __restrict__ bias,
                  float* __restrict__ C,
                  int M, int N, int K)
{
    __shared__ float As[16][68];
    __shared__ float Bs[16][68];

    const int tid = threadIdx.x;
    const int tx  = tid & 15;
    const int ty  = tid >> 4;
    const int row0 = blockIdx.y * 64;
    const int col0 = blockIdx.x * 64;

    const int lr = tid >> 2;          // 0..63
    const int lk = (tid & 3) << 2;    // 0,4,8,12

    const float* Aptr = A  + (size_t)(row0 + lr) * K + lk;
    const float* Bptr = Bm + (size_t)(col0 + lr) * K + lk;

    float acc[4][4] = {};
    float4 av = *reinterpret_cast<const float4*>(Aptr);
    float4 bv = *reinterpret_cast<const float4*>(Bptr);

    const int NT = K >> 4;
    for (int kt = 0; kt < NT; ++kt) {
        __syncthreads();
        As[lk + 0][lr] = av.x; As[lk + 1][lr] = av.y;
        As[lk + 2][lr] = av.z; As[lk + 3][lr] = av.w;
        Bs[lk + 0][lr] = bv.x; Bs[lk + 1][lr] = bv.y;
        Bs[lk + 2][lr] = bv.z; Bs[lk + 3][lr] = bv.w;
        __syncthreads();

        if (kt + 1 < NT) {
            av = *reinterpret_cast<const float4*>(Aptr + (kt + 1) * 16);
            bv = *reinterpret_cast<const float4*>(Bptr + (kt + 1) * 16);
        }

        #pragma unroll
        for (int k = 0; k < 16; ++k) {
            float4 a = *reinterpret_cast<const float4*>(&As[k][ty * 4]);
            float4 bb = *reinterpret_cast<const float4*>(&Bs[k][tx * 4]);
            acc[0][0] = fmaf(a.x, bb.x, acc[0][0]);
            acc[0][1] = fmaf(a.x, bb.y, acc[0][1]);
            acc[0][2] = fmaf(a.x, bb.z, acc[0][2]);
            acc[0][3] = fmaf(a.x, bb.w, acc[0][3]);
            acc[1][0] = fmaf(a.y, bb.x, acc[1][0]);
            acc[1][1] = fmaf(a.y, bb.y, acc[1][1]);
            acc[1][2] = fmaf(a.y, bb.z, acc[1][2]);
            acc[1][3] = fmaf(a.y, bb.w, acc[1][3]);
            acc[2][0] = fmaf(a.z, bb.x, acc[2][0]);
            acc[2][1] = fmaf(a.z, bb.y, acc[2][1]);
            acc[2][2] = fmaf(a.z, bb.z, acc[2][2]);
            acc[2][3] = fmaf(a.z, bb.w, acc[2][3]);
            acc[3][0] = fmaf(a.w, bb.x, acc[3][0]);
            acc[3][1] = fmaf(a.w, bb.y, acc[3][1]);
            acc[3][2] = fmaf(a.w, bb.z, acc[3][2]);
            acc[3][3] = fmaf(a.w, bb.w, acc[3][3]);
        }
    }

    const float4 bb = *reinterpret_cast<const float4*>(&bias[col0 + tx * 4]);
    #pragma unroll
    for (int i = 0; i < 4; ++i) {
        float4 o;
        o.x = acc[i][0] + bb.x;
        o.y = acc[i][1] + bb.y;
        o.z = acc[i][2] + bb.z;
        o.w = acc[i][3] + bb.w;
        *reinterpret_cast<float4*>(&C[(size_t)(row0 + ty * 4 + i) * N + col0 + tx * 4]) = o;
    }
}

// =====================================================================
extern "C" void kernel_launch(void* const* d_in, const int* in_sizes, int n_in,
                              void* d_out, int out_size, void* d_ws, size_t ws_size,
                              hipStream_t stream)
{
    const float* x   = (const float*)d_in[0];  // (4,1024,512)
    const float* W1  = (const float*)d_in[1];  // (2048,512)
    const float* b1  = (const float*)d_in[2];  // (2048)
    const float* W2  = (const float*)d_in[3];  // (512,2048)
    const float* b2  = (const float*)d_in[4];  // (512)
    const float* Lam = (const float*)d_in[5];  // (2048,512)
    const float* Gam = (const float*)d_in[6];  // (2048,512)
    float* out  = (float*)d_out;               // (4,1024,512)
    float* hbuf = (float*)d_ws;                // (4096, 2048) f32 = 32 MB

    const int M = BSZ * LSEQ;                  // 4096

    // 1) static_h = x @ W1^T + b1  -> hbuf
    gemm_nt_bias<<<dim3(DFF / 64, M / 64), dim3(256), 0, stream>>>(
        x, W1, b1, hbuf, M, DFF, DM);

    // 2) scan: hbuf <- h_pre (in place)
    stp_scan<<<dim3(BSZ * (DFF / 8)), dim3(256), 0, stream>>>(x, Lam, Gam, hbuf);

    // 3) hbuf <- gelu(hbuf)
    gelu_inplace<<<dim3(2048), dim3(256), 0, stream>>>(
        reinterpret_cast<float4*>(hbuf), M * DFF / 4);

    // 4) out = hbuf @ W2^T + b2
    gemm_nt_bias<<<dim3(DM / 64, M / 64), dim3(256), 0, stream>>>(
        hbuf, W2, b2, out, M, DM, DFF);
}